// Round 1
// baseline (160410.461 us; speedup 1.0000x reference)
//
#include <hip/hip_runtime.h>
#include <math.h>

// Problem dims
#define NBATCH 4096
#define LSEQ   32
#define FDIM   28
#define HDIM   512
#define KTOT   544     // HDIM + LSEQ
#define GBLK   64      // serial-phase blocks
#define SLICE  8       // HDIM / GBLK hidden cols per block

// ws layout (float words)
#define OFF_X   0u                        // x[4096][32][28]
#define OFF_UA  (OFF_X  + 4096u*896u)     // u_a[4096][28]
#define OFF_WT  (OFF_UA + 4096u*28u)      // Wt[544][2048]
#define OFF_BG  (OFF_WT + 544u*2048u)     // BiasG[2048]
#define OFF_H   (OFF_BG + 2048u)          // hbuf[2][32][512]
#define OFF_BAR (OFF_H  + 2u*32u*512u)    // barrier ints (256 words)
// total ~4.93M floats ~= 19.7 MB of d_ws

__device__ __forceinline__ float sigm(float v) { return 1.0f / (1.0f + __expf(-v)); }

// ---------------- Phase 1a: conv1 residual block + u_a ----------------
__global__ __launch_bounds__(256) void prep_kernel(
    const float* __restrict__ input, const float* __restrict__ masks,
    const float* __restrict__ c1w, const float* __restrict__ c1b,
    const float* __restrict__ convw, const float* __restrict__ convb,
    float* __restrict__ xout, float* __restrict__ uaout)
{
    __shared__ float in_lds[32][28];
    __shared__ float w_lds[28][28][3];
    __shared__ float xo[32][28];
    __shared__ float m_lds[32];
    __shared__ float cb_lds[28];
    const int b = blockIdx.x, tid = threadIdx.x;

    for (int i = tid; i < 896; i += 256) in_lds[i / 28][i % 28] = input[(size_t)b * 896 + i];
    for (int i = tid; i < 2352; i += 256) {
        int o = i / 84, r = i % 84;
        w_lds[o][r / 3][r % 3] = c1w[i];
    }
    if (tid < 32) m_lds[tid] = masks[b * 32 + tid];
    if (tid < 28) cb_lds[tid] = c1b[tid];
    __syncthreads();

    for (int i = tid; i < 896; i += 256) {
        const int l = i / 28, f = i % 28;
        float acc = cb_lds[f];
        for (int ii = 0; ii < 28; ++ii) {
            if (l > 0)  acc = fmaf(in_lds[l - 1][ii], w_lds[f][ii][0], acc);
            acc = fmaf(in_lds[l][ii], w_lds[f][ii][1], acc);
            if (l < 31) acc = fmaf(in_lds[l + 1][ii], w_lds[f][ii][2], acc);
        }
        float v = acc * m_lds[l];
        v = (v > 0.f) ? v : expm1f(v);   // ELU (alpha=1)
        v += in_lds[l][f];               // residual
        xo[l][f] = v;
        xout[(size_t)b * 896 + i] = v;
    }
    __syncthreads();
    if (tid < 28) {
        float s = convb[0];
        for (int l = 0; l < 32; ++l) s = fmaf(xo[l][tid], convw[l], s);
        uaout[b * 28 + tid] = s;
    }
}

// ---------------- Phase 1b: fuse/transpose weights ----------------
// Wt[k][g]: k<512 -> W_hh[g][k]; k=512+j -> W_ih[g][j].  BG[g]=b_ih+b_hh.
__global__ __launch_bounds__(256) void prepw_kernel(
    const float* __restrict__ Wih, const float* __restrict__ Whh,
    const float* __restrict__ bih, const float* __restrict__ bhh,
    float* __restrict__ Wt, float* __restrict__ BG)
{
    const int g = blockIdx.x * 256 + threadIdx.x;  // 0..2047
    for (int k = 0; k < 512; ++k) Wt[(size_t)k * 2048 + g] = Whh[(size_t)g * 512 + k];
    for (int j = 0; j < 32; ++j)  Wt[(size_t)(512 + j) * 2048 + g] = Wih[g * 32 + j];
    BG[g] = bih[g] + bhh[g];
}

// block 0 output projection for batch bb from staged h (cols 0..511)
__device__ __forceinline__ void out_proj(const float* h_lds, const float* c2w, float c2b,
                                         const float* masks, float* out, int bb, int tid)
{
    const int l = tid >> 3, seg = tid & 7;
    const float* hp = h_lds + l * 548;
    float p = 0.f;
    // interleaved k to avoid 8-way LDS bank conflict (seg*64 stride hits same bank)
    for (int k = 0; k < 64; ++k) p = fmaf(hp[seg + 8 * k], c2w[seg + 8 * k], p);
    p += __shfl_xor(p, 1); p += __shfl_xor(p, 2); p += __shfl_xor(p, 4);
    if (seg == 0) out[bb * 32 + l] = (p + c2b) * masks[bb * 32 + l];
}

// ---------------- Phase 2: persistent serial RNN ----------------
__global__ __launch_bounds__(256, 1) void rnn_serial(
    const float* __restrict__ xbuf, const float* __restrict__ uabuf,
    const float* __restrict__ Wt, const float* __restrict__ BG,
    float* hbuf, int* bar,
    const float* __restrict__ bias_mat, const float* __restrict__ masks,
    const float* __restrict__ fc1w, const float* __restrict__ fc1bp,
    const float* __restrict__ c2w, const float* __restrict__ c2bp,
    float* __restrict__ out)
{
    __shared__ float h_lds[32 * 548];     // [32][548]: cols 0..511 h, 512..543 ctx
    __shared__ float x_lds[32][29];
    __shared__ float attn_lds[32][29];
    __shared__ float wa_lds[32];
    __shared__ float gl[32][33];
    __shared__ float c_lds[32][8];

    const int tid  = threadIdx.x;
    const int blk  = blockIdx.x;
    const int lane = tid & 63;
    const int wv   = tid >> 6;
    const int cg   = lane >> 3;       // 0..7: which 4-col group
    const int kc   = lane & 7;        // 0..7: which k-chunk of 68
    const int s0   = blk * SLICE;
    const int gate_t = cg >> 1;       // 0..3 (i,f,g,o)
    const int half   = cg & 1;
    const int Gc   = gate_t * 512 + s0 + half * 4;   // global gate col base (x4 contiguous)

    // W slice resident in registers for the whole kernel: wreg[k 0..67][4 cols]
    float wreg[68][4];
    {
        const float* wp = Wt + (size_t)(kc * 68) * 2048 + Gc;
        #pragma unroll
        for (int k = 0; k < 68; ++k) {
            const float4 w = *(const float4*)(wp + (size_t)k * 2048);
            wreg[k][0] = w.x; wreg[k][1] = w.y; wreg[k][2] = w.z; wreg[k][3] = w.w;
        }
    }
    const float4 bg4 = *(const float4*)(BG + Gc);
    const float f1b = fc1bp[0];
    const float c2b = c2bp[0];

    c_lds[tid >> 3][tid & 7] = 0.f;   // c0 = 0 (256 cells, one per thread)

    int* cnt = bar;
    int* gen = bar + 64;

    for (int b = 0; b < NBATCH; ++b) {
        const int cur = b & 1;
        float* hsrc = hbuf + cur * 16384;
        // stage h (SYSTEM-scope relaxed = sc0+sc1 bypass, coherent via L3) and x[b]
        for (int i = tid; i < 16384; i += 256) {
            float v = __hip_atomic_load(hsrc + i, __ATOMIC_RELAXED, __HIP_MEMORY_SCOPE_SYSTEM);
            h_lds[(i >> 9) * 548 + (i & 511)] = v;
        }
        for (int i = tid; i < 896; i += 256) x_lds[i / 28][i % 28] = xbuf[(size_t)b * 896 + i];
        __syncthreads();

        // w_a[l] = h[l,:] . fc1_w  (8 lanes per row, interleaved k, shuffle reduce)
        {
            const int l = tid >> 3, seg = tid & 7;
            const float* hp = h_lds + l * 548;
            float p = 0.f;
            for (int k = 0; k < 64; ++k) p = fmaf(hp[seg + 8 * k], fc1w[seg + 8 * k], p);
            p += __shfl_xor(p, 1); p += __shfl_xor(p, 2); p += __shfl_xor(p, 4);
            if (seg == 0) wa_lds[l] = p + f1b;
        }
        // out[b-1] from the freshly staged h (state b == h_new of batch b-1)
        if (blk == 0 && b > 0) out_proj(h_lds, c2w, c2b, masks, out, b - 1, tid);
        __syncthreads();

        // softmax over l per feature column f (28 columns)
        if (tid < FDIM) {
            const int f = tid;
            const float uaf = uabuf[b * 28 + f];
            const float* bm = bias_mat + (size_t)b * 896 + f;
            float mx = -1e30f;
            for (int l = 0; l < 32; ++l) {
                float z = uaf + wa_lds[l];
                z = (z >= 0.f) ? z : 0.01f * z;   // leaky_relu(., 0.01)
                z += bm[l * 28];
                attn_lds[l][f] = z;
                mx = fmaxf(mx, z);
            }
            float sum = 0.f;
            for (int l = 0; l < 32; ++l) {
                float e = __expf(attn_lds[l][f] - mx);
                attn_lds[l][f] = e;
                sum += e;
            }
            const float inv = 1.0f / sum;
            for (int l = 0; l < 32; ++l) attn_lds[l][f] *= inv;
        }
        __syncthreads();

        // ctx[l][j] = sum_f attn[l][f] * x[b][j][f]  -> h_lds cols 512..543
        {
            const int l = tid >> 3, j0 = (tid & 7) * 4;
            float t0 = 0, t1 = 0, t2 = 0, t3 = 0;
            for (int f = 0; f < 28; ++f) {
                const float a = attn_lds[l][f];
                t0 = fmaf(a, x_lds[j0 + 0][f], t0);
                t1 = fmaf(a, x_lds[j0 + 1][f], t1);
                t2 = fmaf(a, x_lds[j0 + 2][f], t2);
                t3 = fmaf(a, x_lds[j0 + 3][f], t3);
            }
            float* cp = h_lds + l * 548 + 512 + j0;
            cp[0] = t0; cp[1] = t1; cp[2] = t2; cp[3] = t3;
        }
        __syncthreads();

        // gates: [32 rows] x [32 block cols], K=544; W in regs, h broadcast from LDS
        {
            for (int li = 0; li < 8; ++li) {
                const int l = wv * 8 + li;
                const float* hrow = h_lds + l * 548 + kc * 68;
                float a0 = 0, a1 = 0, a2 = 0, a3 = 0;
                #pragma unroll
                for (int k = 0; k < 68; k += 4) {
                    const float4 h4 = *(const float4*)(hrow + k);
                    a0 = fmaf(h4.x, wreg[k][0], a0);     a1 = fmaf(h4.x, wreg[k][1], a1);
                    a2 = fmaf(h4.x, wreg[k][2], a2);     a3 = fmaf(h4.x, wreg[k][3], a3);
                    a0 = fmaf(h4.y, wreg[k + 1][0], a0); a1 = fmaf(h4.y, wreg[k + 1][1], a1);
                    a2 = fmaf(h4.y, wreg[k + 1][2], a2); a3 = fmaf(h4.y, wreg[k + 1][3], a3);
                    a0 = fmaf(h4.z, wreg[k + 2][0], a0); a1 = fmaf(h4.z, wreg[k + 2][1], a1);
                    a2 = fmaf(h4.z, wreg[k + 2][2], a2); a3 = fmaf(h4.z, wreg[k + 2][3], a3);
                    a0 = fmaf(h4.w, wreg[k + 3][0], a0); a1 = fmaf(h4.w, wreg[k + 3][1], a1);
                    a2 = fmaf(h4.w, wreg[k + 3][2], a2); a3 = fmaf(h4.w, wreg[k + 3][3], a3);
                }
                a0 += __shfl_xor(a0, 1); a0 += __shfl_xor(a0, 2); a0 += __shfl_xor(a0, 4);
                a1 += __shfl_xor(a1, 1); a1 += __shfl_xor(a1, 2); a1 += __shfl_xor(a1, 4);
                a2 += __shfl_xor(a2, 1); a2 += __shfl_xor(a2, 2); a2 += __shfl_xor(a2, 4);
                a3 += __shfl_xor(a3, 1); a3 += __shfl_xor(a3, 2); a3 += __shfl_xor(a3, 4);
                if (kc == 0) {
                    const int jb = gate_t * 8 + half * 4;
                    gl[l][jb + 0] = a0 + bg4.x; gl[l][jb + 1] = a1 + bg4.y;
                    gl[l][jb + 2] = a2 + bg4.z; gl[l][jb + 3] = a3 + bg4.w;
                }
            }
        }
        __syncthreads();

        // LSTM cell for owned cols + publish h slice
        {
            const int l = tid >> 3, cc = tid & 7;
            const float ig = gl[l][cc], fg = gl[l][8 + cc], gg = gl[l][16 + cc], og = gl[l][24 + cc];
            const float cold = c_lds[l][cc];
            const float cn = sigm(fg) * cold + sigm(ig) * tanhf(gg);
            const float hn = sigm(og) * tanhf(cn);
            c_lds[l][cc] = cn;
            float* hdst = hbuf + (cur ^ 1) * 16384 + l * 512 + s0 + cc;
            __hip_atomic_store(hdst, hn, __ATOMIC_RELAXED, __HIP_MEMORY_SCOPE_SYSTEM);
        }

        // one grid barrier per step (monotone epoch). __syncthreads drains vmcnt
        // so all waves' sc1 stores are at L3 before thread 0 arrives.
        __syncthreads();
        if (tid == 0) {
            int a = __hip_atomic_fetch_add(cnt, 1, __ATOMIC_ACQ_REL, __HIP_MEMORY_SCOPE_SYSTEM);
            if (a == GBLK - 1) {
                __hip_atomic_store(cnt, 0, __ATOMIC_RELAXED, __HIP_MEMORY_SCOPE_SYSTEM);
                __hip_atomic_fetch_add(gen, 1, __ATOMIC_RELEASE, __HIP_MEMORY_SCOPE_SYSTEM);
            } else {
                while (__hip_atomic_load(gen, __ATOMIC_RELAXED, __HIP_MEMORY_SCOPE_SYSTEM) < b + 1) {
                    __builtin_amdgcn_s_sleep(1);
                }
            }
        }
        __syncthreads();
    }

    // final output row: h after batch 4095 lives in hbuf[0]
    if (blk == 0) {
        for (int i = tid; i < 16384; i += 256) {
            float v = __hip_atomic_load(hbuf + i, __ATOMIC_RELAXED, __HIP_MEMORY_SCOPE_SYSTEM);
            h_lds[(i >> 9) * 548 + (i & 511)] = v;
        }
        __syncthreads();
        out_proj(h_lds, c2w, c2b, masks, out, NBATCH - 1, tid);
    }
}

extern "C" void kernel_launch(void* const* d_in, const int* in_sizes, int n_in,
                              void* d_out, int out_size, void* d_ws, size_t ws_size,
                              hipStream_t stream)
{
    const float* input    = (const float*)d_in[0];
    const float* masks    = (const float*)d_in[1];
    const float* bias_mat = (const float*)d_in[2];
    const float* c1w      = (const float*)d_in[3];
    const float* c1b      = (const float*)d_in[4];
    const float* convw    = (const float*)d_in[5];
    const float* convb    = (const float*)d_in[6];
    const float* fc1w     = (const float*)d_in[7];
    const float* fc1b     = (const float*)d_in[8];
    const float* Wih      = (const float*)d_in[9];
    const float* Whh      = (const float*)d_in[10];
    const float* bih      = (const float*)d_in[11];
    const float* bhh      = (const float*)d_in[12];
    const float* c2w      = (const float*)d_in[13];
    const float* c2b      = (const float*)d_in[14];

    float* ws  = (float*)d_ws;
    float* out = (float*)d_out;

    // zero h ping-pong buffers + barrier words (each launch; replay-safe)
    hipMemsetAsync(ws + OFF_H, 0, (2u * 32u * 512u + 256u) * sizeof(float), stream);

    hipLaunchKernelGGL(prep_kernel, dim3(NBATCH), dim3(256), 0, stream,
                       input, masks, c1w, c1b, convw, convb, ws + OFF_X, ws + OFF_UA);
    hipLaunchKernelGGL(prepw_kernel, dim3(8), dim3(256), 0, stream,
                       Wih, Whh, bih, bhh, ws + OFF_WT, ws + OFF_BG);
    hipLaunchKernelGGL(rnn_serial, dim3(GBLK), dim3(256), 0, stream,
                       ws + OFF_X, ws + OFF_UA, ws + OFF_WT, ws + OFF_BG,
                       ws + OFF_H, (int*)(ws + OFF_BAR),
                       bias_mat, masks, fc1w, fc1b, c2w, c2b, out);
}

// Round 2
// 103377.576 us; speedup vs baseline: 1.5517x; 1.5517x over previous
//
#include <hip/hip_runtime.h>
#include <math.h>

// Problem dims
#define NBATCH 4096
#define LSEQ   32
#define FDIM   28
#define HDIM   512
#define KTOT   544     // HDIM + LSEQ
#define GBLK   64      // serial-phase blocks
#define SLICE  8       // HDIM / GBLK hidden cols per block

// ws layout (float words)
#define OFF_X   0u                        // x[4096][32][28]
#define OFF_UA  (OFF_X  + 4096u*896u)     // u_a[4096][28]
#define OFF_WT  (OFF_UA + 4096u*28u)      // Wt[544][2048]
#define OFF_BG  (OFF_WT + 544u*2048u)     // BiasG[2048]
#define OFF_H   (OFF_BG + 2048u)          // hbuf[2][32][512]
#define OFF_BAR (OFF_H  + 2u*32u*512u)    // barrier ints (256 words)

__device__ __forceinline__ float sigm(float v) { return 1.0f / (1.0f + __expf(-v)); }

// ---------------- Phase 1a: conv1 residual block + u_a ----------------
__global__ __launch_bounds__(256) void prep_kernel(
    const float* __restrict__ input, const float* __restrict__ masks,
    const float* __restrict__ c1w, const float* __restrict__ c1b,
    const float* __restrict__ convw, const float* __restrict__ convb,
    float* __restrict__ xout, float* __restrict__ uaout)
{
    __shared__ float in_lds[32][28];
    __shared__ float w_lds[28][28][3];
    __shared__ float xo[32][28];
    __shared__ float m_lds[32];
    __shared__ float cb_lds[28];
    const int b = blockIdx.x, tid = threadIdx.x;

    for (int i = tid; i < 896; i += 256) in_lds[i / 28][i % 28] = input[(size_t)b * 896 + i];
    for (int i = tid; i < 2352; i += 256) {
        int o = i / 84, r = i % 84;
        w_lds[o][r / 3][r % 3] = c1w[i];
    }
    if (tid < 32) m_lds[tid] = masks[b * 32 + tid];
    if (tid < 28) cb_lds[tid] = c1b[tid];
    __syncthreads();

    for (int i = tid; i < 896; i += 256) {
        const int l = i / 28, f = i % 28;
        float acc = cb_lds[f];
        for (int ii = 0; ii < 28; ++ii) {
            if (l > 0)  acc = fmaf(in_lds[l - 1][ii], w_lds[f][ii][0], acc);
            acc = fmaf(in_lds[l][ii], w_lds[f][ii][1], acc);
            if (l < 31) acc = fmaf(in_lds[l + 1][ii], w_lds[f][ii][2], acc);
        }
        float v = acc * m_lds[l];
        v = (v > 0.f) ? v : expm1f(v);   // ELU (alpha=1)
        v += in_lds[l][f];               // residual
        xo[l][f] = v;
        xout[(size_t)b * 896 + i] = v;
    }
    __syncthreads();
    if (tid < 28) {
        float s = convb[0];
        for (int l = 0; l < 32; ++l) s = fmaf(xo[l][tid], convw[l], s);
        uaout[b * 28 + tid] = s;
    }
}

// ---------------- Phase 1b: fuse/transpose weights ----------------
__global__ __launch_bounds__(256) void prepw_kernel(
    const float* __restrict__ Wih, const float* __restrict__ Whh,
    const float* __restrict__ bih, const float* __restrict__ bhh,
    float* __restrict__ Wt, float* __restrict__ BG)
{
    const int g = blockIdx.x * 256 + threadIdx.x;  // 0..2047
    for (int k = 0; k < 512; ++k) Wt[(size_t)k * 2048 + g] = Whh[(size_t)g * 512 + k];
    for (int j = 0; j < 32; ++j)  Wt[(size_t)(512 + j) * 2048 + g] = Wih[g * 32 + j];
    BG[g] = bih[g] + bhh[g];
}

// out projection for batch bb from staged h (cols 0..511 of h_lds)
__device__ __forceinline__ void out_proj(const float* h_lds, const float* c2w, float c2b,
                                         const float* masks, float* out, int bb, int tid)
{
    const int l = tid >> 3, seg = tid & 7;
    const float* hp = h_lds + l * 548;
    float p = 0.f;
    for (int k = 0; k < 64; ++k) p = fmaf(hp[seg + 8 * k], c2w[seg + 8 * k], p);
    p += __shfl_xor(p, 1); p += __shfl_xor(p, 2); p += __shfl_xor(p, 4);
    if (seg == 0) out[bb * 32 + l] = (p + c2b) * masks[bb * 32 + l];
}

// ---------------- Phase 2: persistent serial RNN ----------------
__global__ __launch_bounds__(256, 1) void rnn_serial(
    const float* __restrict__ xbuf, const float* __restrict__ uabuf,
    const float* __restrict__ Wt, const float* __restrict__ BG,
    float* hbuf, int* bar,
    const float* __restrict__ bias_mat, const float* __restrict__ masks,
    const float* __restrict__ fc1w, const float* __restrict__ fc1bp,
    const float* __restrict__ c2w, const float* __restrict__ c2bp,
    float* __restrict__ out)
{
    __shared__ float h_lds[32 * 548];     // [32][548]: cols 0..511 h, 512..543 ctx
    __shared__ float x_lds[32][29];
    __shared__ float bias_lds[32][29];
    __shared__ float attn_lds[32][29];
    __shared__ float gpart[4][32][33];    // per-wave gate partials
    __shared__ float wa_lds[32];
    __shared__ float ua_lds[28];

    const int tid  = threadIdx.x;
    const int blk  = blockIdx.x;
    const int lane = tid & 63;
    const int wv   = tid >> 6;
    const int s0   = blk * SLICE;

    // --- gate GEMM layout: 16 col-pairs x 16 k-chunks of 34; 68 W regs/thread ---
    const int pair  = lane & 15;              // 0..15 -> block cols {2p, 2p+1}
    const int chunk = wv * 4 + (lane >> 4);   // 0..15 -> k in [chunk*34, chunk*34+34)
    const int c0    = 2 * pair;
    const int gc0   = (c0 >> 3) * 512 + s0 + (c0 & 7);   // global gate col (pair contiguous)

    float wreg[34][2];
    {
        const float* wp = Wt + (size_t)(chunk * 34) * 2048 + gc0;
        #pragma unroll
        for (int k = 0; k < 34; ++k) {
            const float2 w = *(const float2*)(wp + (size_t)k * 2048);
            wreg[k][0] = w.x; wreg[k][1] = w.y;
        }
    }

    // --- w_a weights in registers (interleaved k) ---
    const int seg = tid & 7;
    float wf[64];
    #pragma unroll
    for (int k = 0; k < 64; ++k) wf[k] = fc1w[seg + 8 * k];

    const int l_own = tid >> 3;   // row for w_a / ctx / LSTM
    const int hc    = tid & 7;    // owned hidden col within slice
    float bg[4];
    #pragma unroll
    for (int g = 0; g < 4; ++g) bg[g] = BG[g * 512 + s0 + hc];
    const float f1b = fc1bp[0];
    const float c2b = c2bp[0];
    float c_reg = 0.f;            // owned LSTM cell state

    int* cnt = bar;               // monotone barrier counter

    for (int b = 0; b < NBATCH; ++b) {
        const int cur = b & 1;

        // 1. stage h from L3 (sc-bypass relaxed loads, 8B each)
        {
            const unsigned long long* hs = (const unsigned long long*)(hbuf + cur * 16384);
            #pragma unroll 4
            for (int it = 0; it < 32; ++it) {
                const int i = it * 256 + tid;
                unsigned long long v = __hip_atomic_load(
                    (unsigned long long*)(hs + i), __ATOMIC_RELAXED, __HIP_MEMORY_SCOPE_AGENT);
                const float2 f2 = __builtin_bit_cast(float2, v);
                const int w = i * 2;
                *(float2*)(h_lds + (w >> 9) * 548 + (w & 511)) = f2;
            }
        }
        // 2. issue x/bias/ua loads early (consumed after next syncs)
        float4 xr = make_float4(0.f, 0.f, 0.f, 0.f), br = xr;
        if (tid < 224) {
            xr = *(const float4*)(xbuf + (size_t)b * 896 + tid * 4);
            br = *(const float4*)(bias_mat + (size_t)b * 896 + tid * 4);
        }
        if (tid < 28) ua_lds[tid] = uabuf[b * 28 + tid];
        __syncthreads();

        // 3. w_a[l] = h[l,:] . fc1_w
        {
            const float* hp = h_lds + l_own * 548;
            float p = 0.f;
            #pragma unroll
            for (int k = 0; k < 64; ++k) p = fmaf(hp[seg + 8 * k], wf[k], p);
            p += __shfl_xor(p, 1); p += __shfl_xor(p, 2); p += __shfl_xor(p, 4);
            if (seg == 0) wa_lds[l_own] = p + f1b;
        }
        // out[b-1] from freshly staged h; rotate the owning block
        if (b > 0 && blk == ((b - 1) & 63)) out_proj(h_lds, c2w, c2b, masks, out, b - 1, tid);

        // 4. park x/bias into LDS
        if (tid < 224) {
            #pragma unroll
            for (int i = 0; i < 4; ++i) {
                const int idx = tid * 4 + i;
                const int l = idx / 28, f = idx - l * 28;
                x_lds[l][f]    = ((const float*)&xr)[i];
                bias_lds[l][f] = ((const float*)&br)[i];
            }
        }
        __syncthreads();

        // 5. softmax over l, per feature f (8 lanes/f, 4 rows each)
        if (tid < 224) {
            const int f = tid >> 3, ls = tid & 7;
            const float uaf = ua_lds[f];
            float z[4];
            #pragma unroll
            for (int r = 0; r < 4; ++r) {
                const int l = ls + 8 * r;
                float v = uaf + wa_lds[l];
                v = (v >= 0.f) ? v : 0.01f * v;      // leaky_relu 0.01
                z[r] = v + bias_lds[l][f];
            }
            float mx = fmaxf(fmaxf(z[0], z[1]), fmaxf(z[2], z[3]));
            mx = fmaxf(mx, __shfl_xor(mx, 1));
            mx = fmaxf(mx, __shfl_xor(mx, 2));
            mx = fmaxf(mx, __shfl_xor(mx, 4));
            float s = 0.f;
            #pragma unroll
            for (int r = 0; r < 4; ++r) { z[r] = __expf(z[r] - mx); s += z[r]; }
            s += __shfl_xor(s, 1); s += __shfl_xor(s, 2); s += __shfl_xor(s, 4);
            const float inv = 1.0f / s;
            #pragma unroll
            for (int r = 0; r < 4; ++r) attn_lds[ls + 8 * r][f] = z[r] * inv;
        }
        __syncthreads();

        // 6. ctx[l][j] = sum_f attn[l][f] * x[j][f]  -> h_lds cols 512..543
        {
            const int j0 = (tid & 7) * 4;
            float t0 = 0, t1 = 0, t2 = 0, t3 = 0;
            #pragma unroll 4
            for (int f = 0; f < 28; ++f) {
                const float a = attn_lds[l_own][f];
                t0 = fmaf(a, x_lds[j0 + 0][f], t0);
                t1 = fmaf(a, x_lds[j0 + 1][f], t1);
                t2 = fmaf(a, x_lds[j0 + 2][f], t2);
                t3 = fmaf(a, x_lds[j0 + 3][f], t3);
            }
            float* cp = h_lds + l_own * 548 + 512 + j0;
            cp[0] = t0; cp[1] = t1; cp[2] = t2; cp[3] = t3;
        }
        __syncthreads();

        // 7. gates: per thread 2 cols x 34 k over 32 rows; broadcast LDS reads
        {
            #pragma unroll 2
            for (int l = 0; l < 32; ++l) {
                const float* hrow = h_lds + l * 548 + chunk * 34;
                float a0 = 0.f, a1 = 0.f;
                #pragma unroll
                for (int kk = 0; kk < 17; ++kk) {
                    const float2 h2 = *(const float2*)(hrow + 2 * kk);
                    a0 = fmaf(h2.x, wreg[2 * kk][0], a0);
                    a1 = fmaf(h2.x, wreg[2 * kk][1], a1);
                    a0 = fmaf(h2.y, wreg[2 * kk + 1][0], a0);
                    a1 = fmaf(h2.y, wreg[2 * kk + 1][1], a1);
                }
                a0 += __shfl_xor(a0, 16); a0 += __shfl_xor(a0, 32);
                a1 += __shfl_xor(a1, 16); a1 += __shfl_xor(a1, 32);
                if (lane < 16) *(float2*)&gpart[wv][l][2 * pair] = make_float2(a0, a1);
            }
        }
        __syncthreads();

        // 8. combine 4 wave-partials + bias, LSTM cell, publish h slice
        {
            float g0 = bg[0], g1 = bg[1], g2 = bg[2], g3 = bg[3];
            #pragma unroll
            for (int w = 0; w < 4; ++w) {
                const float* gp = gpart[w][l_own];
                g0 += gp[hc]; g1 += gp[8 + hc]; g2 += gp[16 + hc]; g3 += gp[24 + hc];
            }
            const float cn = sigm(g1) * c_reg + sigm(g0) * tanhf(g2);
            const float hn = sigm(g3) * tanhf(cn);
            c_reg = cn;
            __hip_atomic_store(hbuf + (cur ^ 1) * 16384 + l_own * 512 + s0 + hc, hn,
                               __ATOMIC_RELAXED, __HIP_MEMORY_SCOPE_AGENT);
        }

        // 9. grid barrier: drain stores, then monotone relaxed counter
        asm volatile("s_waitcnt vmcnt(0)" ::: "memory");
        __syncthreads();
        if (tid == 0) {
            __hip_atomic_fetch_add(cnt, 1, __ATOMIC_RELAXED, __HIP_MEMORY_SCOPE_AGENT);
            const int target = (b + 1) * GBLK;
            while (__hip_atomic_load(cnt, __ATOMIC_RELAXED, __HIP_MEMORY_SCOPE_AGENT) < target)
                __builtin_amdgcn_s_sleep(1);
        }
        __syncthreads();
    }

    // final output row: h after batch 4095 lives in hbuf[0]
    if (blk == 0) {
        for (int it = 0; it < 32; ++it) {
            const int i = it * 256 + tid;
            unsigned long long v = __hip_atomic_load(
                (unsigned long long*)((const unsigned long long*)hbuf + i),
                __ATOMIC_RELAXED, __HIP_MEMORY_SCOPE_AGENT);
            const float2 f2 = __builtin_bit_cast(float2, v);
            const int w = i * 2;
            *(float2*)(h_lds + (w >> 9) * 548 + (w & 511)) = f2;
        }
        __syncthreads();
        out_proj(h_lds, c2w, c2b, masks, out, NBATCH - 1, tid);
    }
}

extern "C" void kernel_launch(void* const* d_in, const int* in_sizes, int n_in,
                              void* d_out, int out_size, void* d_ws, size_t ws_size,
                              hipStream_t stream)
{
    const float* input    = (const float*)d_in[0];
    const float* masks    = (const float*)d_in[1];
    const float* bias_mat = (const float*)d_in[2];
    const float* c1w      = (const float*)d_in[3];
    const float* c1b      = (const float*)d_in[4];
    const float* convw    = (const float*)d_in[5];
    const float* convb    = (const float*)d_in[6];
    const float* fc1w     = (const float*)d_in[7];
    const float* fc1b     = (const float*)d_in[8];
    const float* Wih      = (const float*)d_in[9];
    const float* Whh      = (const float*)d_in[10];
    const float* bih      = (const float*)d_in[11];
    const float* bhh      = (const float*)d_in[12];
    const float* c2w      = (const float*)d_in[13];
    const float* c2b      = (const float*)d_in[14];

    float* ws  = (float*)d_ws;
    float* out = (float*)d_out;

    // zero h ping-pong buffers + barrier words (each launch; replay-safe)
    hipMemsetAsync(ws + OFF_H, 0, (2u * 32u * 512u + 256u) * sizeof(float), stream);

    hipLaunchKernelGGL(prep_kernel, dim3(NBATCH), dim3(256), 0, stream,
                       input, masks, c1w, c1b, convw, convb, ws + OFF_X, ws + OFF_UA);
    hipLaunchKernelGGL(prepw_kernel, dim3(8), dim3(256), 0, stream,
                       Wih, Whh, bih, bhh, ws + OFF_WT, ws + OFF_BG);
    hipLaunchKernelGGL(rnn_serial, dim3(GBLK), dim3(256), 0, stream,
                       ws + OFF_X, ws + OFF_UA, ws + OFF_WT, ws + OFF_BG,
                       ws + OFF_H, (int*)(ws + OFF_BAR),
                       bias_mat, masks, fc1w, fc1b, c2w, c2b, out);
}

// Round 4
// 28780.695 us; speedup vs baseline: 5.5735x; 3.5919x over previous
//
#include <hip/hip_runtime.h>
#include <math.h>

// Problem dims
#define NBATCH 4096
#define LSEQ   32
#define FDIM   28
#define HDIM   512
#define GBLK   64       // worker blocks (8 gate-cols each => 32 gate cols w/ 4 gates)
#define SLICE  8
#define HSTRIDE 548     // h_lds row stride in u32 (row base 16B aligned: 548*4=2192=137*16)
#define XSTR    36

typedef int   i32x4 __attribute__((ext_vector_type(4)));
typedef float f32x4 __attribute__((ext_vector_type(4)));
typedef short short8 __attribute__((ext_vector_type(8)));

// ws layout (4-byte words). TOTAL = 4,933,696 words = 19,734,784 B
// (round-2 used 19,735,552 B successfully; round-3's 25 MB likely overflowed ws)
#define OFF_X    0u                         // x[4096][32][28] f32
#define OFF_UA   (OFF_X  + 4096u*896u)      // u_a[4096][28]
#define OFF_BG   (OFF_UA + 4096u*28u)       // fused gate bias [2048]
#define OFF_H    (OFF_BG + 2048u)           // u32 hbuf[2][32][512], packed bf16 hi|lo
#define OFF_BAR  (OFF_H  + 2u*32u*512u)     // barrier ints (64 words)
#define OFF_WFH  (OFF_BAR + 64u)            // W frags hi: 64blk*17t*2ct*64lane i32x4 = 557056 w
#define OFF_WFL  (OFF_WFH + 557056u)        // W frags lo: 557056 w

// ---- bf16 hi/lo helpers ----
__device__ __forceinline__ unsigned bfr(float x) {            // f32 -> bf16 bits (RNE)
    unsigned u = __builtin_bit_cast(unsigned, x);
    return (u + 0x7FFFu + ((u >> 16) & 1u)) >> 16;
}
__device__ __forceinline__ float fb(unsigned b) { return __builtin_bit_cast(float, b << 16); }
__device__ __forceinline__ unsigned packhl(float v) {          // hi in [15:0], lo in [31:16]
    unsigned h = bfr(v);
    unsigned l = bfr(v - fb(h));
    return h | (l << 16);
}
__device__ __forceinline__ float up(unsigned u) {              // unpack hi+lo -> ~f32
    return __builtin_bit_cast(float, u << 16) + __builtin_bit_cast(float, u & 0xFFFF0000u);
}
__device__ __forceinline__ float sigm(float v) { return 1.0f / (1.0f + __expf(-v)); }

// ---------------- Phase 1a: conv1 residual block + u_a (proven) ----------------
__global__ __launch_bounds__(256) void prep_kernel(
    const float* __restrict__ input, const float* __restrict__ masks,
    const float* __restrict__ c1w, const float* __restrict__ c1b,
    const float* __restrict__ convw, const float* __restrict__ convb,
    float* __restrict__ xout, float* __restrict__ uaout)
{
    __shared__ float in_lds[32][28];
    __shared__ float w_lds[28][28][3];
    __shared__ float xo[32][28];
    __shared__ float m_lds[32];
    __shared__ float cb_lds[28];
    const int b = blockIdx.x, tid = threadIdx.x;

    for (int i = tid; i < 896; i += 256) in_lds[i / 28][i % 28] = input[(size_t)b * 896 + i];
    for (int i = tid; i < 2352; i += 256) {
        int o = i / 84, r = i % 84;
        w_lds[o][r / 3][r % 3] = c1w[i];
    }
    if (tid < 32) m_lds[tid] = masks[b * 32 + tid];
    if (tid < 28) cb_lds[tid] = c1b[tid];
    __syncthreads();

    for (int i = tid; i < 896; i += 256) {
        const int l = i / 28, f = i % 28;
        float acc = cb_lds[f];
        for (int ii = 0; ii < 28; ++ii) {
            if (l > 0)  acc = fmaf(in_lds[l - 1][ii], w_lds[f][ii][0], acc);
            acc = fmaf(in_lds[l][ii], w_lds[f][ii][1], acc);
            if (l < 31) acc = fmaf(in_lds[l + 1][ii], w_lds[f][ii][2], acc);
        }
        float v = acc * m_lds[l];
        v = (v > 0.f) ? v : expm1f(v);   // ELU
        v += in_lds[l][f];               // residual
        xo[l][f] = v;
        xout[(size_t)b * 896 + i] = v;
    }
    __syncthreads();
    if (tid < 28) {
        float s = convb[0];
        for (int l = 0; l < 32; ++l) s = fmaf(xo[l][tid], convw[l], s);
        uaout[b * 28 + tid] = s;
    }
}

// ---------------- Phase 1b: fused gate bias ----------------
__global__ __launch_bounds__(256) void prepw_kernel(
    const float* __restrict__ bih, const float* __restrict__ bhh, float* __restrict__ BG)
{
    const int g = blockIdx.x * 256 + threadIdx.x;
    BG[g] = bih[g] + bhh[g];
}

// ---------------- Phase 1c: W -> MFMA B-fragments, bf16 hi/lo split ----------------
// frag idx = ((blk*17 + t)*2 + ct)*64 + lane (each i32x4).
// Lane holds B[k][n]: n = lane&15, k = t*32 + (lane>>4)*8 + e (e=0..7, even e in low half).
// Local col c = ct*16 + n; gate tg = c>>3; hc = c&7; global g = tg*512 + blk*8 + hc.
__global__ __launch_bounds__(256) void prepf_kernel(
    const float* __restrict__ Wih, const float* __restrict__ Whh,
    unsigned* __restrict__ wfh, unsigned* __restrict__ wfl)
{
    const int id = blockIdx.x * 256 + threadIdx.x;   // 0..139263
    const int lane = id & 63;
    int rest = id >> 6;
    const int ct = rest & 1; rest >>= 1;
    const int t = rest % 17, blk = rest / 17;
    const int n = lane & 15, kg = lane >> 4;
    const int c = ct * 16 + n;
    const int g = (c >> 3) * 512 + blk * 8 + (c & 7);
    const int kbase = t * 32 + kg * 8;
    i32x4 hv, lv;
    #pragma unroll
    for (int d = 0; d < 4; ++d) {
        const int k = kbase + 2 * d;
        float w0 = (k     < 512) ? Whh[(size_t)g * 512 + k]     : Wih[g * 32 + (k - 512)];
        float w1 = (k + 1 < 512) ? Whh[(size_t)g * 512 + k + 1] : Wih[g * 32 + (k + 1 - 512)];
        unsigned h0 = bfr(w0), h1 = bfr(w1);
        unsigned l0 = bfr(w0 - fb(h0)), l1 = bfr(w1 - fb(h1));
        ((unsigned*)&hv)[d] = h0 | (h1 << 16);
        ((unsigned*)&lv)[d] = l0 | (l1 << 16);
    }
    ((i32x4*)wfh)[id] = hv;
    ((i32x4*)wfl)[id] = lv;
}

// ---- pipelined device-scope h staging: 8 dwordx4 in flight, ONE waitcnt ----
// (round-2 used 32 serial atomic loads == ~10.7us/step; this is ~2 round trips)
__device__ __forceinline__ void stage8(const unsigned* p, unsigned* h_lds, int tid, int r)
{
    i32x4 v0, v1, v2, v3, v4, v5, v6, v7;
    asm volatile(
        "global_load_dwordx4 %0, %8, off sc0 sc1\n\t"
        "global_load_dwordx4 %1, %9, off sc0 sc1\n\t"
        "global_load_dwordx4 %2, %10, off sc0 sc1\n\t"
        "global_load_dwordx4 %3, %11, off sc0 sc1\n\t"
        "global_load_dwordx4 %4, %12, off sc0 sc1\n\t"
        "global_load_dwordx4 %5, %13, off sc0 sc1\n\t"
        "global_load_dwordx4 %6, %14, off sc0 sc1\n\t"
        "global_load_dwordx4 %7, %15, off sc0 sc1\n\t"
        "s_waitcnt vmcnt(0)"
        : "=&v"(v0), "=&v"(v1), "=&v"(v2), "=&v"(v3),
          "=&v"(v4), "=&v"(v5), "=&v"(v6), "=&v"(v7)
        : "v"(p), "v"(p + 1024), "v"(p + 2048), "v"(p + 3072),
          "v"(p + 4096), "v"(p + 5120), "v"(p + 6144), "v"(p + 7168)
        : "memory");
    const int col = (tid & 127) * 4;
    const int rb = 16 * r + (tid >> 7);
    *(i32x4*)&h_lds[(rb +  0) * HSTRIDE + col] = v0;
    *(i32x4*)&h_lds[(rb +  2) * HSTRIDE + col] = v1;
    *(i32x4*)&h_lds[(rb +  4) * HSTRIDE + col] = v2;
    *(i32x4*)&h_lds[(rb +  6) * HSTRIDE + col] = v3;
    *(i32x4*)&h_lds[(rb +  8) * HSTRIDE + col] = v4;
    *(i32x4*)&h_lds[(rb + 10) * HSTRIDE + col] = v5;
    *(i32x4*)&h_lds[(rb + 12) * HSTRIDE + col] = v6;
    *(i32x4*)&h_lds[(rb + 14) * HSTRIDE + col] = v7;
}
__device__ __forceinline__ void stage_h(const unsigned* hsrc, unsigned* h_lds, int tid)
{
    stage8(hsrc + tid * 4,        h_lds, tid, 0);
    stage8(hsrc + tid * 4 + 8192, h_lds, tid, 1);
}

// ---- A-fragment build: 8 packed u32 (k..k+7) -> (hi, lo) short8 via v_perm ----
__device__ __forceinline__ void build_frag(const unsigned* base, short8& hi, short8& lo)
{
    i32x4 ua = *(const i32x4*)base;
    i32x4 ub = *(const i32x4*)(base + 4);
    i32x4 h, l;
    h.x = (int)__builtin_amdgcn_perm((unsigned)ua.y, (unsigned)ua.x, 0x05040100u);
    l.x = (int)__builtin_amdgcn_perm((unsigned)ua.y, (unsigned)ua.x, 0x07060302u);
    h.y = (int)__builtin_amdgcn_perm((unsigned)ua.w, (unsigned)ua.z, 0x05040100u);
    l.y = (int)__builtin_amdgcn_perm((unsigned)ua.w, (unsigned)ua.z, 0x07060302u);
    h.z = (int)__builtin_amdgcn_perm((unsigned)ub.y, (unsigned)ub.x, 0x05040100u);
    l.z = (int)__builtin_amdgcn_perm((unsigned)ub.y, (unsigned)ub.x, 0x07060302u);
    h.w = (int)__builtin_amdgcn_perm((unsigned)ub.w, (unsigned)ub.z, 0x05040100u);
    l.w = (int)__builtin_amdgcn_perm((unsigned)ub.w, (unsigned)ub.z, 0x07060302u);
    hi = __builtin_bit_cast(short8, h);
    lo = __builtin_bit_cast(short8, l);
}

// exact f32 gate dot (self-check + fallback): reads original Whh/Wih from d_in
__device__ __forceinline__ float exact_gate(const unsigned* hrow,
    const float* __restrict__ Whh, const float* __restrict__ Wih, int g)
{
    const f32x4* wr = (const f32x4*)(Whh + (size_t)g * 512);
    float s = 0.f;
    #pragma unroll 4
    for (int q = 0; q < 128; ++q) {
        f32x4 w = wr[q];
        s += up(hrow[4 * q + 0]) * w.x + up(hrow[4 * q + 1]) * w.y
           + up(hrow[4 * q + 2]) * w.z + up(hrow[4 * q + 3]) * w.w;
    }
    const float* wi = Wih + g * 32;
    #pragma unroll 8
    for (int j = 0; j < 32; ++j) s += up(hrow[512 + j]) * wi[j];
    return s;
}

// out projection for batch bb from staged h (rows via slot16, u32 packed)
__device__ __forceinline__ void out_proj(const unsigned* h_lds, const float* c2w_lds, float c2b,
                                         const float* masks, float* out, int bb,
                                         int slot16, int seg16)
{
    float p0 = 0.f, p1 = 0.f;
    #pragma unroll
    for (int jj = 0; jj < 8; ++jj) {
        const int off = seg16 * 4 + 64 * jj;
        f32x4 w = *(const f32x4*)&c2w_lds[off];
        i32x4 h0 = *(const i32x4*)&h_lds[slot16 * HSTRIDE + off];
        i32x4 h1 = *(const i32x4*)&h_lds[(slot16 + 16) * HSTRIDE + off];
        p0 += up((unsigned)h0.x) * w.x + up((unsigned)h0.y) * w.y
            + up((unsigned)h0.z) * w.z + up((unsigned)h0.w) * w.w;
        p1 += up((unsigned)h1.x) * w.x + up((unsigned)h1.y) * w.y
            + up((unsigned)h1.z) * w.z + up((unsigned)h1.w) * w.w;
    }
    p0 += __shfl_xor(p0, 1); p0 += __shfl_xor(p0, 2);
    p0 += __shfl_xor(p0, 4); p0 += __shfl_xor(p0, 8);
    p1 += __shfl_xor(p1, 1); p1 += __shfl_xor(p1, 2);
    p1 += __shfl_xor(p1, 4); p1 += __shfl_xor(p1, 8);
    if (seg16 == 0) {
        out[bb * 32 + slot16]      = (p0 + c2b) * masks[bb * 32 + slot16];
        out[bb * 32 + slot16 + 16] = (p1 + c2b) * masks[bb * 32 + slot16 + 16];
    }
}

// ---------------- Phase 2: persistent serial RNN (64 blocks, proven barrier) ----------------
__global__ __launch_bounds__(256, 1) void rnn_serial(
    const float* __restrict__ xbuf, const float* __restrict__ uabuf,
    const float* __restrict__ BG,
    const unsigned* __restrict__ wfh, const unsigned* __restrict__ wfl,
    const float* __restrict__ Whh, const float* __restrict__ Wih,
    unsigned* hbuf, int* bar,
    const float* __restrict__ bias_mat, const float* __restrict__ masks,
    const float* __restrict__ fc1w, const float* __restrict__ fc1bp,
    const float* __restrict__ c2w, const float* __restrict__ c2bp,
    float* __restrict__ out)
{
    __shared__ unsigned h_lds[32 * HSTRIDE];   // packed h (0..511) + ctx (512..543)
    __shared__ float x_lds[32 * XSTR];
    __shared__ float bias_lds[32 * XSTR];
    __shared__ float attn_lds[32 * XSTR];
    __shared__ float gl_part[4 * 32 * 33];     // per-wave gate partials
    __shared__ float wa_lds[32];
    __shared__ float ua_lds[28];
    __shared__ float fc1_lds[512];
    __shared__ float c2w_lds[512];
    __shared__ int   s_flag;

    const int tid  = threadIdx.x;
    const int blk  = blockIdx.x;
    const int lane = tid & 63;
    const int wv   = tid >> 6;

    for (int i = tid; i < 512; i += 256) { fc1_lds[i] = fc1w[i]; c2w_lds[i] = c2w[i]; }
    if (tid == 0) s_flag = 0;
    const float f1b = fc1bp[0];
    const float c2b = c2bp[0];

    // ---- W MFMA fragments resident in registers: wave wv owns k-tiles t0..t0+nt-1 ----
    const int nt = (wv < 3) ? 4 : 5;
    const int t0 = (wv < 3) ? wv * 4 : 12;
    i32x4 whi[5][2], wlo[5][2];
    {
        const i32x4* wfh4 = (const i32x4*)wfh;
        const i32x4* wfl4 = (const i32x4*)wfl;
        for (int s = 0; s < 5; ++s) {
            if (s < nt) {
                #pragma unroll
                for (int ct = 0; ct < 2; ++ct) {
                    const int idx = ((blk * 17 + t0 + s) * 2 + ct) * 64 + lane;
                    whi[s][ct] = wfh4[idx];
                    wlo[s][ct] = wfl4[idx];
                }
            }
        }
    }

    const int l_own = tid >> 3, hc = tid & 7;      // owned LSTM cell (l_own, blk*8+hc)
    float bgv[4];
    #pragma unroll
    for (int t = 0; t < 4; ++t) bgv[t] = BG[t * 512 + blk * 8 + hc];
    float c_reg = 0.f;
    bool use_mfma = true;

    // prefetch x/bias/ua for b=0
    float4 xr = make_float4(0.f, 0.f, 0.f, 0.f), br = xr;
    float ua_r = 0.f;
    if (tid < 224) {
        xr = *(const float4*)(xbuf + tid * 4);
        br = *(const float4*)(bias_mat + tid * 4);
    }
    if (tid < 28) ua_r = uabuf[tid];

    const int slot16 = tid >> 4, seg16 = tid & 15;
    const int arow = lane & 15, kg = lane >> 4;
    int* cnt = bar;
    __syncthreads();

    for (int b = 0; b < NBATCH; ++b) {
        // ---- phase 1: stage h (pipelined, device-scope) + park x/bias/ua ----
        stage_h(hbuf + (b & 1) * 16384, h_lds, tid);
        if (tid < 224) {
            #pragma unroll
            for (int i = 0; i < 4; ++i) {
                const int idx = tid * 4 + i;
                const int l = idx / 28, f = idx - l * 28;
                x_lds[l * XSTR + f]    = ((const float*)&xr)[i];
                bias_lds[l * XSTR + f] = ((const float*)&br)[i];
            }
        }
        if (tid < 28) ua_lds[tid] = ua_r;
        __syncthreads();

        // ---- phase 2: w_a[l] = h[l,:512] . fc1 ; rotating out_proj(b-1) ----
        {
            float p0 = 0.f, p1 = 0.f;
            #pragma unroll
            for (int jj = 0; jj < 8; ++jj) {
                const int off = seg16 * 4 + 64 * jj;
                f32x4 w = *(const f32x4*)&fc1_lds[off];
                i32x4 h0 = *(const i32x4*)&h_lds[slot16 * HSTRIDE + off];
                i32x4 h1 = *(const i32x4*)&h_lds[(slot16 + 16) * HSTRIDE + off];
                p0 += up((unsigned)h0.x) * w.x + up((unsigned)h0.y) * w.y
                    + up((unsigned)h0.z) * w.z + up((unsigned)h0.w) * w.w;
                p1 += up((unsigned)h1.x) * w.x + up((unsigned)h1.y) * w.y
                    + up((unsigned)h1.z) * w.z + up((unsigned)h1.w) * w.w;
            }
            p0 += __shfl_xor(p0, 1); p0 += __shfl_xor(p0, 2);
            p0 += __shfl_xor(p0, 4); p0 += __shfl_xor(p0, 8);
            p1 += __shfl_xor(p1, 1); p1 += __shfl_xor(p1, 2);
            p1 += __shfl_xor(p1, 4); p1 += __shfl_xor(p1, 8);
            if (seg16 == 0) { wa_lds[slot16] = p0 + f1b; wa_lds[slot16 + 16] = p1 + f1b; }
        }
        if (b > 0 && blk == ((b - 1) & 63))
            out_proj(h_lds, c2w_lds, c2b, masks, out, b - 1, slot16, seg16);
        __syncthreads();

        // ---- phase 3: softmax over l per feature f ----
        if (tid < 224) {
            const int f = tid >> 3, ls = tid & 7;
            const float uaf = ua_lds[f];
            float z[4];
            #pragma unroll
            for (int r = 0; r < 4; ++r) {
                const int l = ls + 8 * r;
                float v = uaf + wa_lds[l];
                v = (v >= 0.f) ? v : 0.01f * v;      // leaky_relu 0.01
                z[r] = v + bias_lds[l * XSTR + f];
            }
            float mx = fmaxf(fmaxf(z[0], z[1]), fmaxf(z[2], z[3]));
            mx = fmaxf(mx, __shfl_xor(mx, 1));
            mx = fmaxf(mx, __shfl_xor(mx, 2));
            mx = fmaxf(mx, __shfl_xor(mx, 4));
            float s = 0.f;
            #pragma unroll
            for (int r = 0; r < 4; ++r) { z[r] = __expf(z[r] - mx); s += z[r]; }
            s += __shfl_xor(s, 1); s += __shfl_xor(s, 2); s += __shfl_xor(s, 4);
            const float inv = 1.0f / s;
            #pragma unroll
            for (int r = 0; r < 4; ++r) attn_lds[(ls + 8 * r) * XSTR + f] = z[r] * inv;
        }
        __syncthreads();

        // ---- phase 4: ctx -> h_lds cols 512..543 (packed); prefetch next x/bias/ua ----
        {
            const int j0 = hc * 4;
            float t0v = 0.f, t1v = 0.f, t2v = 0.f, t3v = 0.f;
            #pragma unroll
            for (int fo = 0; fo < 7; ++fo) {
                f32x4 a4 = *(const f32x4*)&attn_lds[l_own * XSTR + fo * 4];
                f32x4 x0 = *(const f32x4*)&x_lds[(j0 + 0) * XSTR + fo * 4];
                f32x4 x1 = *(const f32x4*)&x_lds[(j0 + 1) * XSTR + fo * 4];
                f32x4 x2 = *(const f32x4*)&x_lds[(j0 + 2) * XSTR + fo * 4];
                f32x4 x3 = *(const f32x4*)&x_lds[(j0 + 3) * XSTR + fo * 4];
                t0v += a4.x * x0.x + a4.y * x0.y + a4.z * x0.z + a4.w * x0.w;
                t1v += a4.x * x1.x + a4.y * x1.y + a4.z * x1.z + a4.w * x1.w;
                t2v += a4.x * x2.x + a4.y * x2.y + a4.z * x2.z + a4.w * x2.w;
                t3v += a4.x * x3.x + a4.y * x3.y + a4.z * x3.z + a4.w * x3.w;
            }
            i32x4 cp;
            cp.x = (int)packhl(t0v); cp.y = (int)packhl(t1v);
            cp.z = (int)packhl(t2v); cp.w = (int)packhl(t3v);
            *(i32x4*)&h_lds[l_own * HSTRIDE + 512 + j0] = cp;
        }
        {
            const int bn = (b + 1 < NBATCH) ? b + 1 : 0;
            if (tid < 224) {
                xr = *(const float4*)(xbuf + (size_t)bn * 896 + tid * 4);
                br = *(const float4*)(bias_mat + (size_t)bn * 896 + tid * 4);
            }
            if (tid < 28) ua_r = uabuf[bn * 28 + tid];
        }
        __syncthreads();

        // ---- phase 5: gate GEMM via MFMA; waves split K (tiles t0..t0+nt-1) ----
        if (use_mfma) {
            f32x4 acc[2][2];
            acc[0][0] = (f32x4){0,0,0,0}; acc[0][1] = (f32x4){0,0,0,0};
            acc[1][0] = (f32x4){0,0,0,0}; acc[1][1] = (f32x4){0,0,0,0};
            #pragma unroll
            for (int s = 0; s < 5; ++s) {
                if (s < nt) {
                    const int k0 = (t0 + s) * 32 + kg * 8;
                    short8 ah0, al0, ah1, al1;
                    build_frag(&h_lds[arow * HSTRIDE + k0], ah0, al0);
                    build_frag(&h_lds[(arow + 16) * HSTRIDE + k0], ah1, al1);
                    #pragma unroll
                    for (int ct = 0; ct < 2; ++ct) {
                        short8 bh = __builtin_bit_cast(short8, whi[s][ct]);
                        short8 bl = __builtin_bit_cast(short8, wlo[s][ct]);
                        acc[ct][0] = __builtin_amdgcn_mfma_f32_16x16x32_bf16(ah0, bh, acc[ct][0], 0, 0, 0);
                        acc[ct][0] = __builtin_amdgcn_mfma_f32_16x16x32_bf16(al0, bh, acc[ct][0], 0, 0, 0);
                        acc[ct][0] = __builtin_amdgcn_mfma_f32_16x16x32_bf16(ah0, bl, acc[ct][0], 0, 0, 0);
                        acc[ct][1] = __builtin_amdgcn_mfma_f32_16x16x32_bf16(ah1, bh, acc[ct][1], 0, 0, 0);
                        acc[ct][1] = __builtin_amdgcn_mfma_f32_16x16x32_bf16(al1, bh, acc[ct][1], 0, 0, 0);
                        acc[ct][1] = __builtin_amdgcn_mfma_f32_16x16x32_bf16(ah1, bl, acc[ct][1], 0, 0, 0);
                    }
                }
            }
            // C/D layout (m89-verified): col = lane&15, row = (lane>>4)*4 + reg
            #pragma unroll
            for (int ct = 0; ct < 2; ++ct)
                #pragma unroll
                for (int rt = 0; rt < 2; ++rt)
                    #pragma unroll
                    for (int r = 0; r < 4; ++r) {
                        const int row = rt * 16 + (lane >> 4) * 4 + r;
                        gl_part[(wv * 32 + row) * 33 + ct * 16 + (lane & 15)] = acc[ct][rt][r];
                    }
        }
        __syncthreads();

        // ---- phase 6: combine + (b<2 self-check / fallback) + LSTM + publish ----
        {
            float gv[4];
            #pragma unroll
            for (int t = 0; t < 4; ++t) {
                float g = bgv[t];
                if (use_mfma) {
                    #pragma unroll
                    for (int w = 0; w < 4; ++w)
                        g += gl_part[(w * 32 + l_own) * 33 + t * 8 + hc];
                }
                gv[t] = g;
            }
            if (b < 2) {
                bool bad = false;
                #pragma unroll
                for (int t = 0; t < 4; ++t) {
                    float ref = bgv[t] + exact_gate(&h_lds[l_own * HSTRIDE], Whh, Wih,
                                                    t * 512 + blk * 8 + hc);
                    if (use_mfma && fabsf(gv[t] - ref) > 0.02f + 0.004f * fabsf(ref)) bad = true;
                    gv[t] = ref;
                }
                if (bad) s_flag = 1;
                __syncthreads();
                use_mfma = use_mfma && (s_flag == 0);
                __syncthreads();
                if (tid == 0) s_flag = 0;
            } else if (!use_mfma) {
                #pragma unroll
                for (int t = 0; t < 4; ++t)
                    gv[t] = bgv[t] + exact_gate(&h_lds[l_own * HSTRIDE], Whh, Wih,
                                                t * 512 + blk * 8 + hc);
            }
            const float cn = sigm(gv[1]) * c_reg + sigm(gv[0]) * tanhf(gv[2]);
            const float hn = sigm(gv[3]) * tanhf(cn);
            c_reg = cn;
            __hip_atomic_store(hbuf + ((b & 1) ^ 1) * 16384 + l_own * 512 + blk * 8 + hc,
                               packhl(hn), __ATOMIC_RELAXED, __HIP_MEMORY_SCOPE_AGENT);
        }

        // ---- phase 7: grid barrier (proven round-2 form) ----
        asm volatile("s_waitcnt vmcnt(0)" ::: "memory");
        __syncthreads();
        if (tid == 0) {
            __hip_atomic_fetch_add(cnt, 1, __ATOMIC_RELAXED, __HIP_MEMORY_SCOPE_AGENT);
            const int target = (b + 1) * GBLK;
            while (__hip_atomic_load(cnt, __ATOMIC_RELAXED, __HIP_MEMORY_SCOPE_AGENT) < target)
                __builtin_amdgcn_s_sleep(1);
        }
        __syncthreads();
    }

    // final output row: h after batch 4095 lives in hbuf[0]
    if (blk == 0) {
        stage_h(hbuf, h_lds, tid);
        __syncthreads();
        out_proj(h_lds, c2w_lds, c2b, masks, out, NBATCH - 1, slot16, seg16);
    }
}

extern "C" void kernel_launch(void* const* d_in, const int* in_sizes, int n_in,
                              void* d_out, int out_size, void* d_ws, size_t ws_size,
                              hipStream_t stream)
{
    const float* input    = (const float*)d_in[0];
    const float* masks    = (const float*)d_in[1];
    const float* bias_mat = (const float*)d_in[2];
    const float* c1w      = (const float*)d_in[3];
    const float* c1b      = (const float*)d_in[4];
    const float* convw    = (const float*)d_in[5];
    const float* convb    = (const float*)d_in[6];
    const float* fc1w     = (const float*)d_in[7];
    const float* fc1b     = (const float*)d_in[8];
    const float* Wih      = (const float*)d_in[9];
    const float* Whh      = (const float*)d_in[10];
    const float* bih      = (const float*)d_in[11];
    const float* bhh      = (const float*)d_in[12];
    const float* c2w      = (const float*)d_in[13];
    const float* c2b      = (const float*)d_in[14];

    float* ws  = (float*)d_ws;
    float* out = (float*)d_out;
    int*   bar = (int*)(ws + OFF_BAR);

    // zero h ping-pong + barrier (contiguous region; replay-safe each launch)
    hipMemsetAsync(ws + OFF_H, 0, (2u * 32u * 512u + 64u) * sizeof(float), stream);

    hipLaunchKernelGGL(prep_kernel, dim3(NBATCH), dim3(256), 0, stream,
                       input, masks, c1w, c1b, convw, convb, ws + OFF_X, ws + OFF_UA);
    hipLaunchKernelGGL(prepw_kernel, dim3(8), dim3(256), 0, stream,
                       bih, bhh, ws + OFF_BG);
    hipLaunchKernelGGL(prepf_kernel, dim3(544), dim3(256), 0, stream,
                       Wih, Whh, (unsigned*)(ws + OFF_WFH), (unsigned*)(ws + OFF_WFL));
    hipLaunchKernelGGL(rnn_serial, dim3(GBLK), dim3(256), 0, stream,
                       ws + OFF_X, ws + OFF_UA, ws + OFF_BG,
                       (const unsigned*)(ws + OFF_WFH), (const unsigned*)(ws + OFF_WFL),
                       Whh, Wih,
                       (unsigned*)(ws + OFF_H), bar,
                       bias_mat, masks, fc1w, fc1b, c2w, c2b, out);
}